// Round 1
// baseline (2229.265 us; speedup 1.0000x reference)
//
#include <hip/hip_runtime.h>
#include <cstdint>
#include <cstddef>

// ---------------------------------------------------------------------------
// myModel_ICDM: 5 two-layer MLPs + 2 pooling GEMMs, all as bf16 MFMA GEMMs.
// GEMM kernel = m97-style: 128x128 tile, BK=32, 4 waves (2x2), 16x16x32 bf16
// MFMA, global_load_lds width-16 staging, operands stored [outer][k] so
// fragment reads are ds_read_b128. C = A[M,K] @ Bt[N,K]^T.
// Runtime dtype detection (fp32 vs bf16 harness inputs) via bit-pattern probe.
// ---------------------------------------------------------------------------

typedef unsigned short u16;
typedef unsigned int u32;
typedef __bf16 bf16_t;
typedef bf16_t bf16x8 __attribute__((ext_vector_type(8)));
typedef float f32x4 __attribute__((ext_vector_type(4)));
typedef u16 u16x4 __attribute__((ext_vector_type(4)));
typedef u16 u16x8 __attribute__((ext_vector_type(8)));

__device__ __forceinline__ u16 f2bf(float x) {  // RNE fp32->bf16
  u32 u = __builtin_bit_cast(u32, x);
  u += 0x7FFFu + ((u >> 16) & 1u);
  return (u16)(u >> 16);
}
__device__ __forceinline__ float bf2f(u16 h) {
  u32 u = ((u32)h) << 16;
  return __builtin_bit_cast(float, u);
}

#define AS1(p) ((__attribute__((address_space(1))) void*)(p))
#define AS3(p) ((__attribute__((address_space(3))) void*)(p))

// --------------------------- dtype detection -------------------------------
// fp32 uniform[0,1): byte1 (bits 8..15) is random mantissa (P in [0x3A,0x40) ~2%)
// bf16 pairs: byte1 is elem0's sign+exponent byte, in [0x3A,0x40) ~98.5%.
__global__ void detect_kernel(const u32* __restrict__ p, int* __restrict__ flag) {
  if (threadIdx.x == 0 && blockIdx.x == 0) {
    int cnt = 0;
    for (int i = 0; i < 64; ++i) {
      u32 b = (p[i] >> 8) & 0xFFu;
      cnt += (b >= 0x3Au && b < 0x40u) ? 1 : 0;
    }
    *flag = (cnt >= 32) ? 1 : 0;  // 1 = bf16 inputs/outputs, 0 = fp32
  }
}

// --------------------------- convert (copy) --------------------------------
__global__ void convert_kernel(const void* __restrict__ src, u16* __restrict__ dst,
                               long n, const int* __restrict__ fl) {
  long i = ((long)blockIdx.x * 256 + threadIdx.x) * 8;
  if (i >= n) return;
  u16x8 r;
  if (*fl) {
    r = *(const u16x8*)((const u16*)src + i);
  } else {
    const float* s = (const float*)src + i;
#pragma unroll
    for (int j = 0; j < 8; ++j) r[j] = f2bf(s[j]);
  }
  *(u16x8*)(dst + i) = r;
}

// --------------------------- transpose-convert -----------------------------
// src [R,C] (fp32 or bf16 per flag) -> dst [C,R] bf16. 32x32 LDS tile.
__global__ void tconv_kernel(const void* __restrict__ src, long soff, u16* __restrict__ dst,
                             int R, int C, const int* __restrict__ fl) {
  __shared__ u16 t[32][33];
  const int dt = *fl;
  const int tx = threadIdx.x & 31, ty = threadIdx.x >> 5;
  const long c0 = (long)blockIdx.x * 32, r0 = (long)blockIdx.y * 32;
#pragma unroll
  for (int r = 0; r < 4; ++r) {
    int rr = ty * 4 + r;
    long off = soff + (r0 + rr) * (long)C + c0 + tx;
    t[rr][tx] = dt ? ((const u16*)src)[off] : f2bf(((const float*)src)[off]);
  }
  __syncthreads();
#pragma unroll
  for (int r = 0; r < 4; ++r) {
    int rr = ty * 4 + r;
    dst[(c0 + rr) * (long)R + r0 + tx] = t[tx][rr];
  }
}

// --------------------------- split-K reduce --------------------------------
// dst[(i/512)*ldd + (i%512)] = bf16(sum of 4 slices). Writes into Event[:,512:].
__global__ void reduce4_kernel(const float* __restrict__ s, long stride,
                               u16* __restrict__ dst, long ldd, long n) {
  long i = (long)blockIdx.x * 256 + threadIdx.x;
  if (i >= n) return;
  float v = s[i] + s[i + stride] + s[i + 2 * stride] + s[i + 3 * stride];
  dst[(i >> 9) * ldd + (i & 511)] = f2bf(v);
}

// --------------------------- GEMM: C = A @ Bt^T ----------------------------
// A [M,K] bf16 (lda), Bt [N,K] bf16 (ldb). Grid (N/128, M/128, zsplit).
// K is the per-z-slice span. Epilogue: +bias, relu, writes to any of:
//   outd (d_out, fp32 or bf16 per flag, element offset odoff, ld ldod)
//   outw (fp32 ws, ld ldow, per-z-slice stride ozstride)   [split-K partials]
//   outb/outb2 (bf16 ws, strided — Event concat targets)
//   outT (bf16 ws transposed [N-major]: outT[col*ldT + row])
__global__ __launch_bounds__(256) void gemm_bt_kernel(
    const u16* __restrict__ A, long lda,
    const u16* __restrict__ Bt, long ldb,
    long K,
    const void* __restrict__ bias, int relu,
    void* __restrict__ outd, long odoff, long ldod,
    float* __restrict__ outw, long ldow, long ozstride,
    u16* __restrict__ outb, long ldob,
    u16* __restrict__ outb2, long ldob2,
    u16* __restrict__ outT, long ldT,
    const int* __restrict__ fl) {
  __shared__ u16 As[128 * 32];
  __shared__ u16 Bs[128 * 32];

  const int t = threadIdx.x;
  const int l = t & 63;
  const int w = t >> 6;
  const int wx = w & 1, wy = w >> 1;
  const long m0 = (long)blockIdx.y * 128;
  const long n0 = (long)blockIdx.x * 128;
  const int dt = *fl;

  const long koff = (long)blockIdx.z * K;
  A += koff;
  Bt += koff;
  if (outw) outw += (long)blockIdx.z * ozstride;

  // staging coords: each lane loads 16B; wave w covers 16 rows per pass.
  const int srow = w * 16 + (l >> 2);
  const int scol = (l & 3) * 8;
  const int la = l & 15, lq = l >> 4;

  f32x4 acc[4][4];
  const f32x4 zero = {0.f, 0.f, 0.f, 0.f};
#pragma unroll
  for (int i = 0; i < 4; ++i)
#pragma unroll
    for (int j = 0; j < 4; ++j) acc[i][j] = zero;

  for (long k0 = 0; k0 < K; k0 += 32) {
#pragma unroll
    for (int r = 0; r < 2; ++r) {
      const u16* ga = A + (m0 + r * 64 + srow) * lda + k0 + scol;
      __builtin_amdgcn_global_load_lds(AS1(ga), AS3(As + (r * 64 + w * 16) * 32), 16, 0, 0);
      const u16* gb = Bt + (n0 + r * 64 + srow) * ldb + k0 + scol;
      __builtin_amdgcn_global_load_lds(AS1(gb), AS3(Bs + (r * 64 + w * 16) * 32), 16, 0, 0);
    }
    __syncthreads();

    bf16x8 af[4], bfr[4];
#pragma unroll
    for (int i = 0; i < 4; ++i) {
      af[i] = *(const bf16x8*)(As + (wy * 64 + i * 16 + la) * 32 + lq * 8);
      bfr[i] = *(const bf16x8*)(Bs + (wx * 64 + i * 16 + la) * 32 + lq * 8);
    }
#pragma unroll
    for (int i = 0; i < 4; ++i)
#pragma unroll
      for (int j = 0; j < 4; ++j)
        acc[i][j] = __builtin_amdgcn_mfma_f32_16x16x32_bf16(af[i], bfr[j], acc[i][j], 0, 0, 0);
    __syncthreads();
  }

  // epilogue: C/D layout col=lane&15, row=(lane>>4)*4+reg
  const long gr0 = m0 + wy * 64;
  const long gc0 = n0 + wx * 64;
#pragma unroll
  for (int i = 0; i < 4; ++i) {
#pragma unroll
    for (int j = 0; j < 4; ++j) {
      const long gc = gc0 + j * 16 + la;
      const long grb = gr0 + i * 16 + lq * 4;
      float bv = 0.f;
      if (bias) bv = dt ? bf2f(((const u16*)bias)[gc]) : ((const float*)bias)[gc];
      float vv[4];
#pragma unroll
      for (int p = 0; p < 4; ++p) {
        float x = acc[i][j][p] + bv;
        if (relu) x = x > 0.f ? x : 0.f;
        vv[p] = x;
      }
      if (outd) {
        if (dt) {
          u16* o = (u16*)outd + odoff;
#pragma unroll
          for (int p = 0; p < 4; ++p) o[(grb + p) * ldod + gc] = f2bf(vv[p]);
        } else {
          float* o = (float*)outd + odoff;
#pragma unroll
          for (int p = 0; p < 4; ++p) o[(grb + p) * ldod + gc] = vv[p];
        }
      }
      if (outw) {
#pragma unroll
        for (int p = 0; p < 4; ++p) outw[(grb + p) * ldow + gc] = vv[p];
      }
      if (outb) {
#pragma unroll
        for (int p = 0; p < 4; ++p) outb[(grb + p) * ldob + gc] = f2bf(vv[p]);
      }
      if (outb2) {
#pragma unroll
        for (int p = 0; p < 4; ++p) outb2[(grb + p) * ldob2 + gc] = f2bf(vv[p]);
      }
      if (outT) {
        u16x4 pk;
#pragma unroll
        for (int p = 0; p < 4; ++p) pk[p] = f2bf(vv[p]);
        *(u16x4*)(outT + gc * ldT + grb) = pk;  // 4 consecutive rows -> 8B store
      }
    }
  }
}

// --------------------------- host-side helpers -----------------------------
static void gemm(hipStream_t st, const u16* A, long lda, const u16* Bt, long ldb,
                 long M, long N, long K, int zsplit,
                 const void* bias, int relu,
                 void* outd, long odoff, long ldod,
                 float* outw, long ldow, long ozstride,
                 u16* outb, long ldob, u16* outb2, long ldob2,
                 u16* outT, long ldT, const int* fl) {
  dim3 g((unsigned)(N / 128), (unsigned)(M / 128), (unsigned)zsplit);
  gemm_bt_kernel<<<g, 256, 0, st>>>(A, lda, Bt, ldb, K, bias, relu, outd, odoff, ldod,
                                    outw, ldow, ozstride, outb, ldob, outb2, ldob2,
                                    outT, ldT, fl);
}

static void tconv(hipStream_t st, const void* src, long soff, u16* dst, int R, int C,
                  const int* fl) {
  tconv_kernel<<<dim3((unsigned)(C / 32), (unsigned)(R / 32)), 256, 0, st>>>(src, soff, dst, R,
                                                                             C, fl);
}

static void conv(hipStream_t st, const void* src, u16* dst, long n, const int* fl) {
  convert_kernel<<<(unsigned)((n / 8 + 255) / 256), 256, 0, st>>>(src, dst, n, fl);
}

extern "C" void kernel_launch(void* const* d_in, const int* in_sizes, int n_in,
                              void* d_out, int out_size, void* d_ws, size_t ws_size,
                              hipStream_t stream) {
  (void)in_sizes; (void)n_in; (void)out_size; (void)ws_size;
  const long NA = 16384, DEV = 4096, H1n = 1024, HD = 512, DM = 4096;

  char* ws = (char*)d_ws;
  // Workspace map (aliased; ~208 MiB total):
  u16* BIG = (u16*)(ws + 0L);           // 134.2 MB: bf16 H_M/H_A/H_D, then H_x^T
  u16* H1B = (u16*)(ws + 134217728L);   // 33.6 MB: hidden activations (bf16)
  float* SUMS = (float*)(ws + 134217728L);  // alias: split-K fp32 partials (4 x 2M)
  u16* HMT = (u16*)(ws + 167772160L);   // 16.8 MB: H_mean^T [512,16384] bf16
  u16* EVA = (u16*)(ws + 184549376L);   // 8.4 MB: EventA [4096,1024] bf16
  u16* EVD = (u16*)(ws + 192937984L);   // 8.4 MB: EventD
  u16* WT1 = (u16*)(ws + 201326592L);   // 8.4 MB: w1^T bf16 (per phase)
  u16* WT2 = (u16*)(ws + 209715200L);   // 8.4 MB: w2^T bf16 (per phase)
  int* FLAG = (int*)(ws + 218103808L);  // dtype flag

  const void* H_A = d_in[0];
  const void* H_D = d_in[1];
  const void* H_M = d_in[2];
  const void *wA1 = d_in[3], *bA1 = d_in[4], *wA2 = d_in[5], *bA2 = d_in[6];
  const void *wD1 = d_in[7], *bD1 = d_in[8], *wD2 = d_in[9], *bD2 = d_in[10];
  const void *wM1 = d_in[11], *bM1 = d_in[12], *wM2 = d_in[13], *bM2 = d_in[14];
  const void *wEA1 = d_in[15], *bEA1 = d_in[16], *wEA2 = d_in[17], *bEA2 = d_in[18];
  const void *wED1 = d_in[19], *bED1 = d_in[20], *wED2 = d_in[21], *bED2 = d_in[22];

  // d_out element offsets (return order): reconA, reconD, HmA, HmD, HmM
  const long O_RA = 0, O_RD = 16777216, O_HA = 33554432, O_HD = 41943040, O_HM = 50331648;

  detect_kernel<<<1, 64, 0, stream>>>((const u32*)H_A, FLAG);

  // ---------------- M phase: H_mean_M -> d_out + EventA/D[:, :512] ----------
  tconv(stream, wM1, 0, WT1, (int)DEV, (int)H1n, FLAG);  // [4096,1024] -> [1024,4096]
  tconv(stream, wM2, 0, WT2, (int)H1n, (int)HD, FLAG);   // [1024,512]  -> [512,1024]
  conv(stream, H_M, BIG, DEV * DEV, FLAG);
  gemm(stream, BIG, DEV, WT1, DEV, DEV, H1n, DEV, 1, bM1, 1,
       nullptr, 0, 0, nullptr, 0, 0, H1B, H1n, nullptr, 0, nullptr, 0, FLAG);
  gemm(stream, H1B, H1n, WT2, H1n, DEV, HD, H1n, 1, bM2, 0,
       d_out, O_HM, HD, nullptr, 0, 0, EVA, 1024, EVD, 1024, nullptr, 0, FLAG);

  // ---------------- A phase: H_mean_A, sum_A --------------------------------
  tconv(stream, wA1, 0, WT1, (int)DEV, (int)H1n, FLAG);
  tconv(stream, wA2, 0, WT2, (int)H1n, (int)HD, FLAG);
  conv(stream, H_A, BIG, NA * DEV, FLAG);
  gemm(stream, BIG, DEV, WT1, DEV, NA, H1n, DEV, 1, bA1, 1,
       nullptr, 0, 0, nullptr, 0, 0, H1B, H1n, nullptr, 0, nullptr, 0, FLAG);
  gemm(stream, H1B, H1n, WT2, H1n, NA, HD, H1n, 1, bA2, 0,
       d_out, O_HA, HD, nullptr, 0, 0, nullptr, 0, nullptr, 0, HMT, NA, FLAG);
  // sum_A = H_A^T @ H_mean_A : transpose H_A into BIG, split-K=4 GEMM, reduce.
  tconv(stream, H_A, 0, BIG, (int)NA, (int)DEV, FLAG);  // BIG = H_A^T [4096,16384]
  gemm(stream, BIG, NA, HMT, NA, DEV, HD, 4096, 4, nullptr, 0,
       nullptr, 0, 0, SUMS, HD, 2097152L, nullptr, 0, nullptr, 0, nullptr, 0, FLAG);
  reduce4_kernel<<<8192, 256, 0, stream>>>(SUMS, 2097152L, EVA + 512, 1024L, DEV * HD);

  // ---------------- EA phase: reconstructA ----------------------------------
  tconv(stream, wEA1, 0, WT1, (int)H1n, (int)H1n, FLAG);
  tconv(stream, wEA2, 0, WT2, (int)H1n, (int)DM, FLAG);  // [1024,4096] -> [4096,1024]
  gemm(stream, EVA, 1024, WT1, H1n, DEV, H1n, H1n, 1, bEA1, 1,
       nullptr, 0, 0, nullptr, 0, 0, H1B, H1n, nullptr, 0, nullptr, 0, FLAG);
  gemm(stream, H1B, H1n, WT2, H1n, DEV, DM, H1n, 1, bEA2, 0,
       d_out, O_RA, DM, nullptr, 0, 0, nullptr, 0, nullptr, 0, nullptr, 0, FLAG);

  // ---------------- D phase: H_mean_D, sum_D --------------------------------
  tconv(stream, wD1, 0, WT1, (int)DEV, (int)H1n, FLAG);
  tconv(stream, wD2, 0, WT2, (int)H1n, (int)HD, FLAG);
  conv(stream, H_D, BIG, NA * DEV, FLAG);
  gemm(stream, BIG, DEV, WT1, DEV, NA, H1n, DEV, 1, bD1, 1,
       nullptr, 0, 0, nullptr, 0, 0, H1B, H1n, nullptr, 0, nullptr, 0, FLAG);
  gemm(stream, H1B, H1n, WT2, H1n, NA, HD, H1n, 1, bD2, 0,
       d_out, O_HD, HD, nullptr, 0, 0, nullptr, 0, nullptr, 0, HMT, NA, FLAG);
  tconv(stream, H_D, 0, BIG, (int)NA, (int)DEV, FLAG);  // BIG = H_D^T
  gemm(stream, BIG, NA, HMT, NA, DEV, HD, 4096, 4, nullptr, 0,
       nullptr, 0, 0, SUMS, HD, 2097152L, nullptr, 0, nullptr, 0, nullptr, 0, FLAG);
  reduce4_kernel<<<8192, 256, 0, stream>>>(SUMS, 2097152L, EVD + 512, 1024L, DEV * HD);

  // ---------------- ED phase: reconstructD ----------------------------------
  tconv(stream, wED1, 0, WT1, (int)H1n, (int)H1n, FLAG);
  tconv(stream, wED2, 0, WT2, (int)H1n, (int)DM, FLAG);
  gemm(stream, EVD, 1024, WT1, H1n, DEV, H1n, H1n, 1, bED1, 1,
       nullptr, 0, 0, nullptr, 0, 0, H1B, H1n, nullptr, 0, nullptr, 0, FLAG);
  gemm(stream, H1B, H1n, WT2, H1n, DEV, DM, H1n, 1, bED2, 0,
       d_out, O_RD, DM, nullptr, 0, 0, nullptr, 0, nullptr, 0, nullptr, 0, FLAG);
}